// Round 10
// baseline (177.776 us; speedup 1.0000x reference)
//
#include <hip/hip_runtime.h>
#include <math.h>

#define N_NODES 40000
#define N_EDGES 640000
#define D 128
#define D_OUT 64
#define SCAN_NBLK 157   // ceil(40000/256)

typedef __attribute__((ext_vector_type(8))) short short8v;   // 8 bf16 = 4 VGPR
typedef __attribute__((ext_vector_type(8))) unsigned short ushort8v;
typedef __attribute__((ext_vector_type(4))) float f32x4;

__device__ __forceinline__ float bf2f(unsigned short u) {
    return __uint_as_float(((unsigned int)u) << 16);
}
__device__ __forceinline__ unsigned short f2bf(float f) {
    unsigned int u = __float_as_uint(f);
    return (unsigned short)((u + 0x7FFFu + ((u >> 16) & 1u)) >> 16);  // RNE
}

// ---- fused prep: bf16 converts + W transposes + degree histogram ----
// (deg/cnt pre-zeroed by hipMemsetAsync; atomics need no intra-kernel ordering)
__global__ __launch_bounds__(256) void k_prep(const float* __restrict__ X,
                                              const float* __restrict__ W1,
                                              const float* __restrict__ W2,
                                              const float* __restrict__ Wp,
                                              const int* __restrict__ tgt,
                                              int* __restrict__ deg,
                                              unsigned short* __restrict__ x_bf,
                                              unsigned short* __restrict__ W1t,
                                              unsigned short* __restrict__ W2t,
                                              unsigned short* __restrict__ Wpt) {
    int i = blockIdx.x * 256 + threadIdx.x;   // grid = 5000 blocks = 1.28M threads
    if (i < 128 * 128) {            // Wt[n*K+k] = W[k*N+n]
        int n = i >> 7, k = i & 127;
        W1t[i] = f2bf(W1[(size_t)k * 128 + n]);
        W2t[i] = f2bf(W2[(size_t)k * 128 + n]);
    }
    if (i < 384 * 64) {
        int n = i / 384, k = i - n * 384;
        Wpt[i] = f2bf(Wp[(size_t)k * 64 + n]);
    }
    if (i < N_NODES * D / 4) {
        float4 v = ((const float4*)X)[i];
        ushort4 o;
        o.x = f2bf(v.x); o.y = f2bf(v.y); o.z = f2bf(v.z); o.w = f2bf(v.w);
        ((ushort4*)x_bf)[i] = o;
    }
    if (i < N_EDGES) atomicAdd(&deg[tgt[i]], 1);
}

// ---------------- CSR scan ----------------
__global__ __launch_bounds__(256) void k_scan1(const int* __restrict__ deg,
                                               int* __restrict__ row_ptr,
                                               int* __restrict__ partials,
                                               float* __restrict__ dis) {
    __shared__ int s[256];
    int t = threadIdx.x;
    int i = blockIdx.x * 256 + t;
    int v = (i < N_NODES) ? deg[i] : 0;
    if (i < N_NODES) dis[i] = rsqrtf((float)v + 1.0f);  // +1 self-loop
    s[t] = v;
    __syncthreads();
    #pragma unroll
    for (int off = 1; off < 256; off <<= 1) {
        int u = (t >= off) ? s[t - off] : 0;
        __syncthreads();
        s[t] += u;
        __syncthreads();
    }
    if (i < N_NODES) row_ptr[i] = s[t] - v;      // block-local exclusive
    if (t == 255) partials[blockIdx.x] = s[255];
}

__global__ __launch_bounds__(256) void k_scan2(int* __restrict__ partials) {
    __shared__ int s[256];
    int t = threadIdx.x;
    int v = (t < SCAN_NBLK) ? partials[t] : 0;
    s[t] = v;
    __syncthreads();
    #pragma unroll
    for (int off = 1; off < 256; off <<= 1) {
        int u = (t >= off) ? s[t - off] : 0;
        __syncthreads();
        s[t] += u;
        __syncthreads();
    }
    if (t < SCAN_NBLK) partials[t] = s[t] - v;   // exclusive
}

// scatter (edge-parallel, local row_ptr + partials) + fused row_ptr
// globalization into a SEPARATE buffer row_ptr_g (no race).
__global__ void k_scatter_fix(const int* __restrict__ tgt, const int* __restrict__ src,
                              const int* __restrict__ row_ptr_loc,
                              const int* __restrict__ partials,
                              int* __restrict__ row_ptr_g,
                              int* __restrict__ cnt,
                              const float* __restrict__ dis,
                              int2* __restrict__ ecc) {
    int e = blockIdx.x * blockDim.x + threadIdx.x;
    if (e <= N_NODES) {
        if (e < N_NODES) row_ptr_g[e] = row_ptr_loc[e] + partials[e >> 8];
        else             row_ptr_g[N_NODES] = N_EDGES;
    }
    if (e >= N_EDGES) return;
    int t = tgt[e];
    int s = src[e];
    int pos = row_ptr_loc[t] + partials[t >> 8] + atomicAdd(&cnt[t], 1);
    ecc[pos] = make_int2(s, __float_as_int(dis[t] * dis[s]));
}

// ---------------- MFMA GEMM: C_bf16[40000 x 128] = A_bf16 @ W (Wt: [128][128]) --
__global__ __launch_bounds__(256) void k_mfma_gemm(const unsigned short* __restrict__ A,
                                                   const unsigned short* __restrict__ Wt,
                                                   unsigned short* __restrict__ C) {
    int w  = threadIdx.x >> 6;
    int l  = threadIdx.x & 63;
    int lr = l & 15;
    int lk = l >> 4;

    short8v wf[2][4];
    #pragma unroll
    for (int nt = 0; nt < 2; ++nt) {
        int n = w * 32 + nt * 16 + lr;
        #pragma unroll
        for (int kc = 0; kc < 4; ++kc)
            wf[nt][kc] = *(const short8v*)(Wt + (size_t)n * 128 + kc * 32 + lk * 8);
    }

    for (int mt = blockIdx.x; mt < 2500; mt += gridDim.x) {
        int m0 = mt * 16;
        f32x4 acc0 = {0.f, 0.f, 0.f, 0.f};
        f32x4 acc1 = {0.f, 0.f, 0.f, 0.f};
        #pragma unroll
        for (int kc = 0; kc < 4; ++kc) {
            short8v a = *(const short8v*)(A + (size_t)(m0 + lr) * 128 + kc * 32 + lk * 8);
            acc0 = __builtin_amdgcn_mfma_f32_16x16x32_bf16(a, wf[0][kc], acc0, 0, 0, 0);
            acc1 = __builtin_amdgcn_mfma_f32_16x16x32_bf16(a, wf[1][kc], acc1, 0, 0, 0);
        }
        int row = m0 + lk * 4;
        int c0  = w * 32 + lr;
        #pragma unroll
        for (int r = 0; r < 4; ++r) {
            C[(size_t)(row + r) * 128 + c0]      = f2bf(acc0[r]);
            C[(size_t)(row + r) * 128 + c0 + 16] = f2bf(acc1[r]);
        }
    }
}

// ---------------- MFMA final: out[40000 x 64] = [x,h1,h2]_bf16 @ Wp + bp ------
__global__ __launch_bounds__(256) void k_mfma_final(const unsigned short* __restrict__ xbf,
                                                    const unsigned short* __restrict__ h1bf,
                                                    const unsigned short* __restrict__ h2bf,
                                                    const unsigned short* __restrict__ Wpt,
                                                    const float* __restrict__ bp,
                                                    float* __restrict__ out) {
    int w  = threadIdx.x >> 6;
    int l  = threadIdx.x & 63;
    int lr = l & 15;
    int lk = l >> 4;

    short8v wf[12];
    {
        int n = w * 16 + lr;
        #pragma unroll
        for (int kc = 0; kc < 12; ++kc)
            wf[kc] = *(const short8v*)(Wpt + (size_t)n * 384 + kc * 32 + lk * 8);
    }
    const unsigned short* srcs[3] = {xbf, h1bf, h2bf};
    float bb = bp[w * 16 + lr];

    for (int mt = blockIdx.x; mt < 2500; mt += gridDim.x) {
        int m0 = mt * 16;
        f32x4 acc = {0.f, 0.f, 0.f, 0.f};
        #pragma unroll
        for (int kc = 0; kc < 12; ++kc) {
            const unsigned short* S = srcs[kc >> 2];
            short8v a = *(const short8v*)(S + (size_t)(m0 + lr) * 128 + (kc & 3) * 32 + lk * 8);
            acc = __builtin_amdgcn_mfma_f32_16x16x32_bf16(a, wf[kc], acc, 0, 0, 0);
        }
        int row = m0 + lk * 4;
        int c   = w * 16 + lr;
        #pragma unroll
        for (int r = 0; r < 4; ++r)
            out[(size_t)(row + r) * 64 + c] = acc[r] + bb;
    }
}

// ---------------- fused CSR aggregate + bias + self-loop + LayerNorm + ReLU ----
// 4 nodes per wave: 16 lanes per node, lane holds 8 dims (ushort8 = 16B load).
// Edge loop unrolled 8-wide (4 aligned int4 record loads, 8 gathers in flight).
__global__ __launch_bounds__(256) void k_agg_ln(const unsigned short* __restrict__ H,
                                                const float* __restrict__ dis,
                                                const int* __restrict__ row_ptr,
                                                const int2* __restrict__ ecc,
                                                const float* __restrict__ b,
                                                const float* __restrict__ g,
                                                const float* __restrict__ be,
                                                unsigned short* __restrict__ OUT) {
    int lh = threadIdx.x & 15;                 // dim group: 8 dims
    int i  = blockIdx.x * 16 + (threadIdx.x >> 4);
    if (i >= N_NODES) return;

    float a[8];
    {
        float   di = dis[i];
        float   c  = di * di;
        ushort8v v = *(const ushort8v*)(H + (size_t)i * D + lh * 8);
        const float4* b4 = (const float4*)(b + lh * 8);
        float4 bb0 = b4[0], bb1 = b4[1];
        a[0] = bb0.x + c * bf2f(v[0]); a[1] = bb0.y + c * bf2f(v[1]);
        a[2] = bb0.z + c * bf2f(v[2]); a[3] = bb0.w + c * bf2f(v[3]);
        a[4] = bb1.x + c * bf2f(v[4]); a[5] = bb1.y + c * bf2f(v[5]);
        a[6] = bb1.z + c * bf2f(v[6]); a[7] = bb1.w + c * bf2f(v[7]);
    }

    int e   = row_ptr[i];
    int end = row_ptr[i + 1];
    if ((e & 1) && e < end) {                   // peel to 16B-align ecc reads
        int2 p = ecc[e];
        float c0 = __int_as_float(p.y);
        ushort8v v = *(const ushort8v*)(H + (size_t)p.x * D + lh * 8);
        #pragma unroll
        for (int j = 0; j < 8; ++j) a[j] += c0 * bf2f(v[j]);
        ++e;
    }
    for (; e + 7 < end; e += 8) {               // 8 edges per iteration
        int4 pA = *(const int4*)&ecc[e];
        int4 pB = *(const int4*)&ecc[e + 2];
        int4 pC = *(const int4*)&ecc[e + 4];
        int4 pD = *(const int4*)&ecc[e + 6];
        ushort8v v0 = *(const ushort8v*)(H + (size_t)pA.x * D + lh * 8);
        ushort8v v1 = *(const ushort8v*)(H + (size_t)pA.z * D + lh * 8);
        ushort8v v2 = *(const ushort8v*)(H + (size_t)pB.x * D + lh * 8);
        ushort8v v3 = *(const ushort8v*)(H + (size_t)pB.z * D + lh * 8);
        ushort8v v4 = *(const ushort8v*)(H + (size_t)pC.x * D + lh * 8);
        ushort8v v5 = *(const ushort8v*)(H + (size_t)pC.z * D + lh * 8);
        ushort8v v6 = *(const ushort8v*)(H + (size_t)pD.x * D + lh * 8);
        ushort8v v7 = *(const ushort8v*)(H + (size_t)pD.z * D + lh * 8);
        float c0 = __int_as_float(pA.y), c1 = __int_as_float(pA.w);
        float c2 = __int_as_float(pB.y), c3 = __int_as_float(pB.w);
        float c4 = __int_as_float(pC.y), c5 = __int_as_float(pC.w);
        float c6 = __int_as_float(pD.y), c7 = __int_as_float(pD.w);
        #pragma unroll
        for (int j = 0; j < 8; ++j) a[j] += c0 * bf2f(v0[j]);
        #pragma unroll
        for (int j = 0; j < 8; ++j) a[j] += c1 * bf2f(v1[j]);
        #pragma unroll
        for (int j = 0; j < 8; ++j) a[j] += c2 * bf2f(v2[j]);
        #pragma unroll
        for (int j = 0; j < 8; ++j) a[j] += c3 * bf2f(v3[j]);
        #pragma unroll
        for (int j = 0; j < 8; ++j) a[j] += c4 * bf2f(v4[j]);
        #pragma unroll
        for (int j = 0; j < 8; ++j) a[j] += c5 * bf2f(v5[j]);
        #pragma unroll
        for (int j = 0; j < 8; ++j) a[j] += c6 * bf2f(v6[j]);
        #pragma unroll
        for (int j = 0; j < 8; ++j) a[j] += c7 * bf2f(v7[j]);
    }
    for (; e + 1 < end; e += 2) {
        int4 p = *(const int4*)&ecc[e];
        ushort8v v0 = *(const ushort8v*)(H + (size_t)p.x * D + lh * 8);
        ushort8v v1 = *(const ushort8v*)(H + (size_t)p.z * D + lh * 8);
        float c0 = __int_as_float(p.y);
        float c1 = __int_as_float(p.w);
        #pragma unroll
        for (int j = 0; j < 8; ++j) a[j] += c0 * bf2f(v0[j]);
        #pragma unroll
        for (int j = 0; j < 8; ++j) a[j] += c1 * bf2f(v1[j]);
    }
    if (e < end) {
        int2 p = ecc[e];
        float c0 = __int_as_float(p.y);
        ushort8v v = *(const ushort8v*)(H + (size_t)p.x * D + lh * 8);
        #pragma unroll
        for (int j = 0; j < 8; ++j) a[j] += c0 * bf2f(v[j]);
    }

    // LayerNorm over 128 dims: 8 local + reduce across 16 lanes
    float s = 0.f;
    #pragma unroll
    for (int j = 0; j < 8; ++j) s += a[j];
    #pragma unroll
    for (int off = 8; off >= 1; off >>= 1) s += __shfl_xor(s, off);
    float mean = s * (1.0f / 128.0f);

    float vs = 0.f;
    #pragma unroll
    for (int j = 0; j < 8; ++j) { a[j] -= mean; vs += a[j] * a[j]; }
    #pragma unroll
    for (int off = 8; off >= 1; off >>= 1) vs += __shfl_xor(vs, off);
    float inv = rsqrtf(vs * (1.0f / 128.0f) + 1e-5f);

    const float4* g4 = (const float4*)(g + lh * 8);
    const float4* e4 = (const float4*)(be + lh * 8);
    float4 g0 = g4[0], g1 = g4[1], e0 = e4[0], e1 = e4[1];
    ushort8v o;
    o[0] = f2bf(fmaxf(a[0] * inv * g0.x + e0.x, 0.0f));
    o[1] = f2bf(fmaxf(a[1] * inv * g0.y + e0.y, 0.0f));
    o[2] = f2bf(fmaxf(a[2] * inv * g0.z + e0.z, 0.0f));
    o[3] = f2bf(fmaxf(a[3] * inv * g0.w + e0.w, 0.0f));
    o[4] = f2bf(fmaxf(a[4] * inv * g1.x + e1.x, 0.0f));
    o[5] = f2bf(fmaxf(a[5] * inv * g1.y + e1.y, 0.0f));
    o[6] = f2bf(fmaxf(a[6] * inv * g1.z + e1.z, 0.0f));
    o[7] = f2bf(fmaxf(a[7] * inv * g1.w + e1.w, 0.0f));
    *(ushort8v*)(OUT + (size_t)i * D + lh * 8) = o;
}

// ---------------- launcher ----------------
extern "C" void kernel_launch(void* const* d_in, const int* in_sizes, int n_in,
                              void* d_out, int out_size, void* d_ws, size_t ws_size,
                              hipStream_t stream) {
    const float* x   = (const float*)d_in[0];
    const int*   ei  = (const int*)  d_in[1];   // [2, E] int32
    const float* W1  = (const float*)d_in[2];
    const float* b1  = (const float*)d_in[3];
    const float* g1  = (const float*)d_in[4];
    const float* be1 = (const float*)d_in[5];
    const float* W2  = (const float*)d_in[6];
    const float* b2  = (const float*)d_in[7];
    const float* g2  = (const float*)d_in[8];
    const float* be2 = (const float*)d_in[9];
    const float* Wp  = (const float*)d_in[10];
    const float* bp  = (const float*)d_in[11];
    float* out = (float*)d_out;

    const int* tgt = ei;
    const int* src = ei + N_EDGES;

    char* ws = (char*)d_ws;
    int*   deg_i   = (int*)   ws;               ws += 40960 * 4;   // adjacent to cnt:
    int*   cnt     = (int*)   ws;               ws += 40960 * 4;   // one memset covers both
    int*   row_ptr = (int*)   ws;               ws += 41984 * 4;   // block-local scan
    int*   row_ptr_g = (int*) ws;               ws += 41984 * 4;   // globalized
    int*   partials= (int*)   ws;               ws += 256 * 4;
    int2*  ecc     = (int2*)  ws;               ws += (size_t)N_EDGES * 8;
    float* dis     = (float*) ws;               ws += 40960 * 4;
    unsigned short* x_bf   = (unsigned short*)ws; ws += (size_t)N_NODES * D * 2;
    unsigned short* tmp_bf = (unsigned short*)ws; ws += (size_t)N_NODES * D * 2;
    unsigned short* h1_bf  = (unsigned short*)ws; ws += (size_t)N_NODES * D * 2;
    unsigned short* h2_bf  = (unsigned short*)ws; ws += (size_t)N_NODES * D * 2;
    unsigned short* W1t    = (unsigned short*)ws; ws += 128 * 128 * 2;
    unsigned short* W2t    = (unsigned short*)ws; ws += 128 * 128 * 2;
    unsigned short* Wpt    = (unsigned short*)ws; ws += 384 * 64 * 2;

    const int B = 256;

    // zero deg+cnt (adjacent) with one async memset, then fused prep+degree
    hipMemsetAsync(deg_i, 0, 2 * 40960 * 4, stream);
    k_prep     <<<5000, B, 0, stream>>>(x, W1, W2, Wp, tgt, deg_i, x_bf, W1t, W2t, Wpt);
    k_scan1    <<<SCAN_NBLK, B, 0, stream>>>(deg_i, row_ptr, partials, dis);
    k_scan2    <<<1, B, 0, stream>>>(partials);
    k_scatter_fix<<<(N_EDGES + B - 1) / B, B, 0, stream>>>(tgt, src, row_ptr, partials,
                                                           row_ptr_g, cnt, dis, ecc);

    // ---- block 1 ----
    k_mfma_gemm<<<1250, B, 0, stream>>>(x_bf, W1t, tmp_bf);
    k_agg_ln   <<<2500, B, 0, stream>>>(tmp_bf, dis, row_ptr_g, ecc, b1, g1, be1, h1_bf);

    // ---- block 2 ----
    k_mfma_gemm<<<1250, B, 0, stream>>>(h1_bf, W2t, tmp_bf);
    k_agg_ln   <<<2500, B, 0, stream>>>(tmp_bf, dis, row_ptr_g, ecc, b2, g2, be2, h2_bf);

    // ---- jumping-knowledge concat + projection ----
    k_mfma_final<<<1250, B, 0, stream>>>(x_bf, h1_bf, h2_bf, Wpt, bp, out);
}

// Round 11
// 170.459 us; speedup vs baseline: 1.0429x; 1.0429x over previous
//
#include <hip/hip_runtime.h>
#include <math.h>

#define N_NODES 40000
#define N_EDGES 640000
#define D 128
#define D_OUT 64
#define SCAN_NBLK 157   // ceil(40000/256)

typedef __attribute__((ext_vector_type(8))) short short8v;   // 8 bf16 = 4 VGPR
typedef __attribute__((ext_vector_type(8))) unsigned short ushort8v;
typedef __attribute__((ext_vector_type(4))) float f32x4;

__device__ __forceinline__ float bf2f(unsigned short u) {
    return __uint_as_float(((unsigned int)u) << 16);
}
__device__ __forceinline__ unsigned short f2bf(float f) {
    unsigned int u = __float_as_uint(f);
    return (unsigned short)((u + 0x7FFFu + ((u >> 16) & 1u)) >> 16);  // RNE
}

// ---- fused prep: bf16 converts + W transposes + degree histogram ----
// (deg/cnt pre-zeroed by hipMemsetAsync; atomics need no intra-kernel ordering)
__global__ __launch_bounds__(256) void k_prep(const float* __restrict__ X,
                                              const float* __restrict__ W1,
                                              const float* __restrict__ W2,
                                              const float* __restrict__ Wp,
                                              const int* __restrict__ tgt,
                                              int* __restrict__ deg,
                                              unsigned short* __restrict__ x_bf,
                                              unsigned short* __restrict__ W1t,
                                              unsigned short* __restrict__ W2t,
                                              unsigned short* __restrict__ Wpt) {
    int i = blockIdx.x * 256 + threadIdx.x;   // grid = 5000 blocks = 1.28M threads
    if (i < 128 * 128) {            // Wt[n*K+k] = W[k*N+n]
        int n = i >> 7, k = i & 127;
        W1t[i] = f2bf(W1[(size_t)k * 128 + n]);
        W2t[i] = f2bf(W2[(size_t)k * 128 + n]);
    }
    if (i < 384 * 64) {
        int n = i / 384, k = i - n * 384;
        Wpt[i] = f2bf(Wp[(size_t)k * 64 + n]);
    }
    if (i < N_NODES * D / 4) {
        float4 v = ((const float4*)X)[i];
        ushort4 o;
        o.x = f2bf(v.x); o.y = f2bf(v.y); o.z = f2bf(v.z); o.w = f2bf(v.w);
        ((ushort4*)x_bf)[i] = o;
    }
    if (i < N_EDGES) atomicAdd(&deg[tgt[i]], 1);
}

// ---------------- CSR scan ----------------
__global__ __launch_bounds__(256) void k_scan1(const int* __restrict__ deg,
                                               int* __restrict__ row_ptr,
                                               int* __restrict__ partials,
                                               float* __restrict__ dis) {
    __shared__ int s[256];
    int t = threadIdx.x;
    int i = blockIdx.x * 256 + t;
    int v = (i < N_NODES) ? deg[i] : 0;
    if (i < N_NODES) dis[i] = rsqrtf((float)v + 1.0f);  // +1 self-loop
    s[t] = v;
    __syncthreads();
    #pragma unroll
    for (int off = 1; off < 256; off <<= 1) {
        int u = (t >= off) ? s[t - off] : 0;
        __syncthreads();
        s[t] += u;
        __syncthreads();
    }
    if (i < N_NODES) row_ptr[i] = s[t] - v;      // block-local exclusive
    if (t == 255) partials[blockIdx.x] = s[255];
}

__global__ __launch_bounds__(256) void k_scan2(int* __restrict__ partials) {
    __shared__ int s[256];
    int t = threadIdx.x;
    int v = (t < SCAN_NBLK) ? partials[t] : 0;
    s[t] = v;
    __syncthreads();
    #pragma unroll
    for (int off = 1; off < 256; off <<= 1) {
        int u = (t >= off) ? s[t - off] : 0;
        __syncthreads();
        s[t] += u;
        __syncthreads();
    }
    if (t < SCAN_NBLK) partials[t] = s[t] - v;   // exclusive
}

// ---------------- shared MFMA GEMM body (Wt: [128 n][128 k] bf16) ----------------
__device__ __forceinline__ void gemm128_body(int blk, int nblk,
                                             const unsigned short* __restrict__ A,
                                             const unsigned short* __restrict__ Wt,
                                             unsigned short* __restrict__ C) {
    int w  = threadIdx.x >> 6;
    int l  = threadIdx.x & 63;
    int lr = l & 15;
    int lk = l >> 4;

    short8v wf[2][4];
    #pragma unroll
    for (int nt = 0; nt < 2; ++nt) {
        int n = w * 32 + nt * 16 + lr;
        #pragma unroll
        for (int kc = 0; kc < 4; ++kc)
            wf[nt][kc] = *(const short8v*)(Wt + (size_t)n * 128 + kc * 32 + lk * 8);
    }

    for (int mt = blk; mt < 2500; mt += nblk) {
        int m0 = mt * 16;
        f32x4 acc0 = {0.f, 0.f, 0.f, 0.f};
        f32x4 acc1 = {0.f, 0.f, 0.f, 0.f};
        #pragma unroll
        for (int kc = 0; kc < 4; ++kc) {
            short8v a = *(const short8v*)(A + (size_t)(m0 + lr) * 128 + kc * 32 + lk * 8);
            acc0 = __builtin_amdgcn_mfma_f32_16x16x32_bf16(a, wf[0][kc], acc0, 0, 0, 0);
            acc1 = __builtin_amdgcn_mfma_f32_16x16x32_bf16(a, wf[1][kc], acc1, 0, 0, 0);
        }
        int row = m0 + lk * 4;
        int c0  = w * 32 + lr;
        #pragma unroll
        for (int r = 0; r < 4; ++r) {
            C[(size_t)(row + r) * 128 + c0]      = f2bf(acc0[r]);
            C[(size_t)(row + r) * 128 + c0 + 16] = f2bf(acc1[r]);
        }
    }
}

__global__ __launch_bounds__(256) void k_mfma_gemm(const unsigned short* __restrict__ A,
                                                   const unsigned short* __restrict__ Wt,
                                                   unsigned short* __restrict__ C) {
    gemm128_body(blockIdx.x, gridDim.x, A, Wt, C);
}

// ---- fused dispatch: blocks 0-2499 CSR-scatter, blocks 2500-3749 gemm1 ----
// (independent work: scatter reads row_ptr/partials/dis; gemm reads x_bf/W1t)
__global__ __launch_bounds__(256) void k_scatter_gemm(
    const int* __restrict__ tgt, const int* __restrict__ src,
    const int* __restrict__ row_ptr_loc, const int* __restrict__ partials,
    int* __restrict__ row_ptr_g, int* __restrict__ cnt,
    const float* __restrict__ dis, int2* __restrict__ ecc,
    const unsigned short* __restrict__ A, const unsigned short* __restrict__ Wt,
    unsigned short* __restrict__ C)
{
    if (blockIdx.x < 2500) {
        int e = blockIdx.x * 256 + threadIdx.x;
        if (e <= N_NODES) {
            if (e < N_NODES) row_ptr_g[e] = row_ptr_loc[e] + partials[e >> 8];
            else             row_ptr_g[N_NODES] = N_EDGES;
        }
        if (e >= N_EDGES) return;
        int t = tgt[e];
        int s = src[e];
        int pos = row_ptr_loc[t] + partials[t >> 8] + atomicAdd(&cnt[t], 1);
        ecc[pos] = make_int2(s, __float_as_int(dis[t] * dis[s]));
    } else {
        gemm128_body(blockIdx.x - 2500, 1250, A, Wt, C);
    }
}

// ---------------- MFMA final: out[40000 x 64] = [x,h1,h2]_bf16 @ Wp + bp ------
__global__ __launch_bounds__(256) void k_mfma_final(const unsigned short* __restrict__ xbf,
                                                    const unsigned short* __restrict__ h1bf,
                                                    const unsigned short* __restrict__ h2bf,
                                                    const unsigned short* __restrict__ Wpt,
                                                    const float* __restrict__ bp,
                                                    float* __restrict__ out) {
    int w  = threadIdx.x >> 6;
    int l  = threadIdx.x & 63;
    int lr = l & 15;
    int lk = l >> 4;

    short8v wf[12];
    {
        int n = w * 16 + lr;
        #pragma unroll
        for (int kc = 0; kc < 12; ++kc)
            wf[kc] = *(const short8v*)(Wpt + (size_t)n * 384 + kc * 32 + lk * 8);
    }
    const unsigned short* srcs[3] = {xbf, h1bf, h2bf};
    float bb = bp[w * 16 + lr];

    for (int mt = blockIdx.x; mt < 2500; mt += gridDim.x) {
        int m0 = mt * 16;
        f32x4 acc = {0.f, 0.f, 0.f, 0.f};
        #pragma unroll
        for (int kc = 0; kc < 12; ++kc) {
            const unsigned short* S = srcs[kc >> 2];
            short8v a = *(const short8v*)(S + (size_t)(m0 + lr) * 128 + (kc & 3) * 32 + lk * 8);
            acc = __builtin_amdgcn_mfma_f32_16x16x32_bf16(a, wf[kc], acc, 0, 0, 0);
        }
        int row = m0 + lk * 4;
        int c   = w * 16 + lr;
        #pragma unroll
        for (int r = 0; r < 4; ++r)
            out[(size_t)(row + r) * 64 + c] = acc[r] + bb;
    }
}

// ---------------- fused CSR aggregate + bias + self-loop + LayerNorm + ReLU ----
// 4 nodes per wave: 16 lanes per node, lane holds 8 dims (ushort8 = 16B load).
// Edge loop unrolled 4-wide (2 aligned int4 record loads, 4 gathers in flight).
__global__ __launch_bounds__(256) void k_agg_ln(const unsigned short* __restrict__ H,
                                                const float* __restrict__ dis,
                                                const int* __restrict__ row_ptr,
                                                const int2* __restrict__ ecc,
                                                const float* __restrict__ b,
                                                const float* __restrict__ g,
                                                const float* __restrict__ be,
                                                unsigned short* __restrict__ OUT) {
    int lh = threadIdx.x & 15;                 // dim group: 8 dims
    int i  = blockIdx.x * 16 + (threadIdx.x >> 4);
    if (i >= N_NODES) return;

    float a[8];
    {
        float   di = dis[i];
        float   c  = di * di;
        ushort8v v = *(const ushort8v*)(H + (size_t)i * D + lh * 8);
        const float4* b4 = (const float4*)(b + lh * 8);
        float4 bb0 = b4[0], bb1 = b4[1];
        a[0] = bb0.x + c * bf2f(v[0]); a[1] = bb0.y + c * bf2f(v[1]);
        a[2] = bb0.z + c * bf2f(v[2]); a[3] = bb0.w + c * bf2f(v[3]);
        a[4] = bb1.x + c * bf2f(v[4]); a[5] = bb1.y + c * bf2f(v[5]);
        a[6] = bb1.z + c * bf2f(v[6]); a[7] = bb1.w + c * bf2f(v[7]);
    }

    int e   = row_ptr[i];
    int end = row_ptr[i + 1];
    if ((e & 1) && e < end) {                   // peel to 16B-align ecc reads
        int2 p = ecc[e];
        float c0 = __int_as_float(p.y);
        ushort8v v = *(const ushort8v*)(H + (size_t)p.x * D + lh * 8);
        #pragma unroll
        for (int j = 0; j < 8; ++j) a[j] += c0 * bf2f(v[j]);
        ++e;
    }
    for (; e + 3 < end; e += 4) {               // 4 edges per iteration
        int4 pA = *(const int4*)&ecc[e];
        int4 pB = *(const int4*)&ecc[e + 2];
        ushort8v v0 = *(const ushort8v*)(H + (size_t)pA.x * D + lh * 8);
        ushort8v v1 = *(const ushort8v*)(H + (size_t)pA.z * D + lh * 8);
        ushort8v v2 = *(const ushort8v*)(H + (size_t)pB.x * D + lh * 8);
        ushort8v v3 = *(const ushort8v*)(H + (size_t)pB.z * D + lh * 8);
        float c0 = __int_as_float(pA.y);
        float c1 = __int_as_float(pA.w);
        float c2 = __int_as_float(pB.y);
        float c3 = __int_as_float(pB.w);
        #pragma unroll
        for (int j = 0; j < 8; ++j) a[j] += c0 * bf2f(v0[j]);
        #pragma unroll
        for (int j = 0; j < 8; ++j) a[j] += c1 * bf2f(v1[j]);
        #pragma unroll
        for (int j = 0; j < 8; ++j) a[j] += c2 * bf2f(v2[j]);
        #pragma unroll
        for (int j = 0; j < 8; ++j) a[j] += c3 * bf2f(v3[j]);
    }
    if (e + 1 < end) {
        int4 p = *(const int4*)&ecc[e];
        ushort8v v0 = *(const ushort8v*)(H + (size_t)p.x * D + lh * 8);
        ushort8v v1 = *(const ushort8v*)(H + (size_t)p.z * D + lh * 8);
        float c0 = __int_as_float(p.y);
        float c1 = __int_as_float(p.w);
        #pragma unroll
        for (int j = 0; j < 8; ++j) a[j] += c0 * bf2f(v0[j]);
        #pragma unroll
        for (int j = 0; j < 8; ++j) a[j] += c1 * bf2f(v1[j]);
        e += 2;
    }
    if (e < end) {
        int2 p = ecc[e];
        float c0 = __int_as_float(p.y);
        ushort8v v = *(const ushort8v*)(H + (size_t)p.x * D + lh * 8);
        #pragma unroll
        for (int j = 0; j < 8; ++j) a[j] += c0 * bf2f(v[j]);
    }

    // LayerNorm over 128 dims: 8 local + reduce across 16 lanes
    float s = 0.f;
    #pragma unroll
    for (int j = 0; j < 8; ++j) s += a[j];
    #pragma unroll
    for (int off = 8; off >= 1; off >>= 1) s += __shfl_xor(s, off);
    float mean = s * (1.0f / 128.0f);

    float vs = 0.f;
    #pragma unroll
    for (int j = 0; j < 8; ++j) { a[j] -= mean; vs += a[j] * a[j]; }
    #pragma unroll
    for (int off = 8; off >= 1; off >>= 1) vs += __shfl_xor(vs, off);
    float inv = rsqrtf(vs * (1.0f / 128.0f) + 1e-5f);

    const float4* g4 = (const float4*)(g + lh * 8);
    const float4* e4 = (const float4*)(be + lh * 8);
    float4 g0 = g4[0], g1 = g4[1], e0 = e4[0], e1 = e4[1];
    ushort8v o;
    o[0] = f2bf(fmaxf(a[0] * inv * g0.x + e0.x, 0.0f));
    o[1] = f2bf(fmaxf(a[1] * inv * g0.y + e0.y, 0.0f));
    o[2] = f2bf(fmaxf(a[2] * inv * g0.z + e0.z, 0.0f));
    o[3] = f2bf(fmaxf(a[3] * inv * g0.w + e0.w, 0.0f));
    o[4] = f2bf(fmaxf(a[4] * inv * g1.x + e1.x, 0.0f));
    o[5] = f2bf(fmaxf(a[5] * inv * g1.y + e1.y, 0.0f));
    o[6] = f2bf(fmaxf(a[6] * inv * g1.z + e1.z, 0.0f));
    o[7] = f2bf(fmaxf(a[7] * inv * g1.w + e1.w, 0.0f));
    *(ushort8v*)(OUT + (size_t)i * D + lh * 8) = o;
}

// ---------------- launcher ----------------
extern "C" void kernel_launch(void* const* d_in, const int* in_sizes, int n_in,
                              void* d_out, int out_size, void* d_ws, size_t ws_size,
                              hipStream_t stream) {
    const float* x   = (const float*)d_in[0];
    const int*   ei  = (const int*)  d_in[1];   // [2, E] int32
    const float* W1  = (const float*)d_in[2];
    const float* b1  = (const float*)d_in[3];
    const float* g1  = (const float*)d_in[4];
    const float* be1 = (const float*)d_in[5];
    const float* W2  = (const float*)d_in[6];
    const float* b2  = (const float*)d_in[7];
    const float* g2  = (const float*)d_in[8];
    const float* be2 = (const float*)d_in[9];
    const float* Wp  = (const float*)d_in[10];
    const float* bp  = (const float*)d_in[11];
    float* out = (float*)d_out;

    const int* tgt = ei;
    const int* src = ei + N_EDGES;

    char* ws = (char*)d_ws;
    int*   deg_i   = (int*)   ws;               ws += 40960 * 4;   // adjacent to cnt:
    int*   cnt     = (int*)   ws;               ws += 40960 * 4;   // one memset covers both
    int*   row_ptr = (int*)   ws;               ws += 41984 * 4;   // block-local scan
    int*   row_ptr_g = (int*) ws;               ws += 41984 * 4;   // globalized
    int*   partials= (int*)   ws;               ws += 256 * 4;
    int2*  ecc     = (int2*)  ws;               ws += (size_t)N_EDGES * 8;
    float* dis     = (float*) ws;               ws += 40960 * 4;
    unsigned short* x_bf   = (unsigned short*)ws; ws += (size_t)N_NODES * D * 2;
    unsigned short* tmp_bf = (unsigned short*)ws; ws += (size_t)N_NODES * D * 2;
    unsigned short* h1_bf  = (unsigned short*)ws; ws += (size_t)N_NODES * D * 2;
    unsigned short* h2_bf  = (unsigned short*)ws; ws += (size_t)N_NODES * D * 2;
    unsigned short* W1t    = (unsigned short*)ws; ws += 128 * 128 * 2;
    unsigned short* W2t    = (unsigned short*)ws; ws += 128 * 128 * 2;
    unsigned short* Wpt    = (unsigned short*)ws; ws += 384 * 64 * 2;

    const int B = 256;

    // zero deg+cnt (adjacent) with one async memset, then fused prep+degree
    hipMemsetAsync(deg_i, 0, 2 * 40960 * 4, stream);
    k_prep     <<<5000, B, 0, stream>>>(x, W1, W2, Wp, tgt, deg_i, x_bf, W1t, W2t, Wpt);
    k_scan1    <<<SCAN_NBLK, B, 0, stream>>>(deg_i, row_ptr, partials, dis);
    k_scan2    <<<1, B, 0, stream>>>(partials);

    // ---- scatter (CSR) + gemm1 (x@W1) overlapped in one dispatch ----
    k_scatter_gemm<<<3750, B, 0, stream>>>(tgt, src, row_ptr, partials,
                                           row_ptr_g, cnt, dis, ecc,
                                           x_bf, W1t, tmp_bf);

    // ---- block 1 aggregate ----
    k_agg_ln   <<<2500, B, 0, stream>>>(tmp_bf, dis, row_ptr_g, ecc, b1, g1, be1, h1_bf);

    // ---- block 2 ----
    k_mfma_gemm<<<1250, B, 0, stream>>>(h1_bf, W2t, tmp_bf);
    k_agg_ln   <<<2500, B, 0, stream>>>(tmp_bf, dis, row_ptr_g, ecc, b2, g2, be2, h2_bf);

    // ---- jumping-knowledge concat + projection ----
    k_mfma_final<<<1250, B, 0, stream>>>(x_bf, h1_bf, h2_bf, Wpt, bp, out);
}